// Round 8
// baseline (355.513 us; speedup 1.0000x reference)
//
#include <hip/hip_runtime.h>

// KDE entropy loss, MI355X/gfx950 — fp8 fused GEMM, symmetric pairs once,
// wrapped-diagonal mapping. 512-thread blocks (8 waves 4x2 over 128x128,
// wave tile 32x64), A-in-registers, double-buffered B, 1 barrier/iter.
// R8: colsum atomics DEFERRED out of the K-loop (R7 paid an atomic write-ack
// vmcnt(0) drain at every iteration barrier). Main loop is compile-time 16
// iters; per-tile colsums live in 16 static VGPRs (lane keeps its j==h half);
// extra t=64 tile peeled. End: LDS cross-wave reduce (buf0) -> 4x fewer atomics.
// ws: [0,4MiB) Xn fp8 [16384][256]; [4MiB,+64KiB) density f32; then ticket u32.

#define NROWS 16384
#define KDIM 256            // bytes per fp8 row
#define NTILE 128
#define NT (NROWS / NTILE)  // 128 tile rows
#define NSTRIP 4
#define TOTAL_BLOCKS (NT * NSTRIP)  // 512 blocks of 512 thr = exactly 2 per CU

// sqrt(5 * log2(e)): folded into both operands -> sim scaled by 5*log2(e),
// so kernel = exp2(sim_scaled) = exp(5*sim).
#define SQRT_KLOG2E 2.68579577857f

typedef int i32x4_t __attribute__((ext_vector_type(4)));
typedef int i32x8_t __attribute__((ext_vector_type(8)));
typedef float f32x16_t __attribute__((ext_vector_type(16)));
typedef __attribute__((address_space(1))) const void global_cvoid_t;
typedef __attribute__((address_space(3))) void lds_void_t;

#if __has_builtin(__builtin_amdgcn_exp2f)
#define EXP2(x) __builtin_amdgcn_exp2f(x)
#else
#define EXP2(x) exp2f(x)
#endif

union frag8 { i32x8_t v8; i32x4_t v4[2]; };

// One wave per row: sqrt(5log2e)/max(||x||,eps), fp8 e4m3 out; zero density+ticket.
__global__ __launch_bounds__(256)
void kde_normalize(const float* __restrict__ X, unsigned int* __restrict__ Xn8,
                   float* __restrict__ density, unsigned int* __restrict__ ticket) {
  const int wave = threadIdx.x >> 6;
  const int lane = threadIdx.x & 63;
  const int row = blockIdx.x * 4 + wave;
  const float4 v = ((const float4*)(X + (size_t)row * KDIM))[lane];
  float ss = v.x * v.x + v.y * v.y + v.z * v.z + v.w * v.w;
  ss += __shfl_xor(ss, 1);
  ss += __shfl_xor(ss, 2);
  ss += __shfl_xor(ss, 4);
  ss += __shfl_xor(ss, 8);
  ss += __shfl_xor(ss, 16);
  ss += __shfl_xor(ss, 32);
  const float scale = SQRT_KLOG2E / fmaxf(sqrtf(ss), 1e-12f);
  int p = 0;
  p = __builtin_amdgcn_cvt_pk_fp8_f32(v.x * scale, v.y * scale, p, false);
  p = __builtin_amdgcn_cvt_pk_fp8_f32(v.z * scale, v.w * scale, p, true);
  Xn8[(size_t)row * 64 + lane] = (unsigned int)p;
  if (threadIdx.x < 4) density[blockIdx.x * 4 + threadIdx.x] = 0.0f;
  if (blockIdx.x == 0 && threadIdx.x == 0) *ticket = 0u;
}

// Block (bi, s): row tile bi; J = (bi+t) mod 128, t in [s*16, s*16+16)
// (+ t=64 peeled for s==0, bi<64). Each unordered tile pair once.
__global__ __launch_bounds__(512, 4)
void kde_gemm(const unsigned char* __restrict__ Xn8, float* __restrict__ density,
              unsigned int* __restrict__ ticket, float* __restrict__ out) {
  extern __shared__ char smem[];
  char* buf0 = smem;           // 32 KB
  char* buf1 = smem + 32768;   // 32 KB

  const int tid = threadIdx.x;
  const int wave = tid >> 6;   // 0..7
  const int lane = tid & 63;
  const int wr = wave >> 1;    // row quarter 0..3 (32 rows each)
  const int wc = wave & 1;     // col half 0..1 (64 cols each)
  const int m32 = lane & 31;
  const int h = lane >> 5;
  const int bi = blockIdx.x;
  const int s = blockIdx.y;
  const int t0 = s * 16;
  const bool extra = (s == 0 && bi < NT / 2);
  const char* Xb = (const char*)Xn8;

  // Chunk c = rt*8 + kb*2 + hh: lane holds M[rt*32+m32][kb*64+h*32+hh*16 ..+15].
#define STAGE(base_row, dst)                                                      \
  for (int c = wave; c < 32; c += 8) {                                            \
    const int rt = c >> 3, kb = (c >> 1) & 3, hh = c & 1;                         \
    const size_t gofs =                                                           \
        (size_t)((base_row) + rt * 32 + m32) * KDIM + kb * 64 + h * 32 + hh * 16; \
    __builtin_amdgcn_global_load_lds((global_cvoid_t*)(Xb + gofs),                \
                                     (lds_void_t*)((dst) + c * 1024), 16, 0, 0);  \
  }

  STAGE(bi * NTILE, buf0);                      // A tile -> buf0
  STAGE(((bi + t0) & (NT - 1)) * NTILE, buf1);  // B(0)   -> buf1
  __syncthreads();  // both landed

  // A fragments -> registers: this wave's 32 rows, full K (32 VGPRs).
  frag8 areg[4];
#pragma unroll
  for (int kb = 0; kb < 4; kb++) {
    const char* pa = buf0 + (wr * 8 + kb * 2) * 1024 + lane * 16;
    areg[kb].v4[0] = *(const i32x4_t*)pa;
    areg[kb].v4[1] = *(const i32x4_t*)(pa + 1024);
  }
  __syncthreads();  // all waves done reading A from buf0

  float rs[16];
#pragma unroll
  for (int r = 0; r < 16; r++) rs[r] = 0.0f;
  float cs_save[16];  // static-indexed (loop fully unrolled): this lane's j==h colsum

#pragma unroll
  for (int k = 0; k < 16; ++k) {
    const int J = (bi + t0 + k) & (NT - 1);
    char* rbuf = (k & 1) ? buf0 : buf1;  // B(k): landed at last barrier
    char* sbuf = (k & 1) ? buf1 : buf0;  // free since last barrier

    if (k < 15) {
      STAGE(((bi + t0 + k + 1) & (NT - 1)) * NTILE, sbuf);
    } else if (extra) {
      STAGE(((bi + 64) & (NT - 1)) * NTILE, sbuf);  // sbuf == buf1 at k==15
    }
    (void)J;

    f32x16_t acc[2];
#pragma unroll
    for (int j = 0; j < 2; j++) acc[j] = (f32x16_t)0.0f;

#pragma unroll
    for (int kb = 0; kb < 4; ++kb) {
      frag8 bf[2];
#pragma unroll
      for (int j = 0; j < 2; j++) {
        const char* pb = rbuf + ((wc * 2 + j) * 8 + kb * 2) * 1024 + lane * 16;
        bf[j].v4[0] = *(const i32x4_t*)pb;
        bf[j].v4[1] = *(const i32x4_t*)(pb + 1024);
      }
#pragma unroll
      for (int j = 0; j < 2; j++)
        acc[j] = __builtin_amdgcn_mfma_scale_f32_32x32x64_f8f6f4(
            areg[kb].v8, bf[j].v8, acc[j], 0, 0, 0, 127, 0, 127);
    }

    // Epilogue (VALU only — no vmem, so the barrier drains only staging):
    // e = exp2(sim_scaled) = exp(5*sim). C/D: col=m32, row=(r&3)+8*(r>>2)+4*h.
    float c0 = 0.0f, c1 = 0.0f;
#pragma unroll
    for (int r = 0; r < 16; r++) {
      const float e0 = EXP2(acc[0][r]);
      const float e1 = EXP2(acc[1][r]);
      rs[r] += e0 + e1;
      c0 += e0;
      c1 += e1;
    }
    c0 += __shfl_xor(c0, 32);  // combine h halves -> 32-row column partial
    c1 += __shfl_xor(c1, 32);
    cs_save[k] = h ? c1 : c0;  // lane keeps the half for column wc*64 + lane

    __syncthreads();  // B(k+1) landed; all waves done reading rbuf
  }

  // Peeled extra tile t=64 (self-paired half): immediate colsum atomics (once).
  if (extra) {
    const int J = (bi + 64) & (NT - 1);
    f32x16_t acc[2];
#pragma unroll
    for (int j = 0; j < 2; j++) acc[j] = (f32x16_t)0.0f;
#pragma unroll
    for (int kb = 0; kb < 4; ++kb) {
      frag8 bf[2];
#pragma unroll
      for (int j = 0; j < 2; j++) {
        const char* pb = buf1 + ((wc * 2 + j) * 8 + kb * 2) * 1024 + lane * 16;
        bf[j].v4[0] = *(const i32x4_t*)pb;
        bf[j].v4[1] = *(const i32x4_t*)(pb + 1024);
      }
#pragma unroll
      for (int j = 0; j < 2; j++)
        acc[j] = __builtin_amdgcn_mfma_scale_f32_32x32x64_f8f6f4(
            areg[kb].v8, bf[j].v8, acc[j], 0, 0, 0, 127, 0, 127);
    }
    float c0 = 0.0f, c1 = 0.0f;
#pragma unroll
    for (int r = 0; r < 16; r++) {
      const float e0 = EXP2(acc[0][r]);
      const float e1 = EXP2(acc[1][r]);
      rs[r] += e0 + e1;
      c0 += e0;
      c1 += e1;
    }
    c0 += __shfl_xor(c0, 32);
    c1 += __shfl_xor(c1, 32);
    if (h == 0) {
      atomicAdd(&density[J * NTILE + wc * 64 + m32], c0);
      atomicAdd(&density[J * NTILE + wc * 64 + 32 + m32], c1);
    }
  }

  // Deferred colsum scatter: cross-wr reduce through buf0 (free after loop).
  // Lane's column id = wc*64 + lane (h*32+m32 == lane). 32 KB = 4wr x 16k x 128col.
  {
    float* csLds = (float*)buf0;
#pragma unroll
    for (int k = 0; k < 16; ++k)
      csLds[(wr * 16 + k) * 128 + wc * 64 + lane] = cs_save[k];
    __syncthreads();
#pragma unroll
    for (int i = 0; i < 4; ++i) {
      const int idx = tid + i * 512;      // 0..2047
      const int k = idx >> 7, col = idx & 127;
      if (s != 0 || k != 0) {             // t==0 diagonal: rowsum only
        const float v = csLds[(0 * 16 + k) * 128 + col] +
                        csLds[(1 * 16 + k) * 128 + col] +
                        csLds[(2 * 16 + k) * 128 + col] +
                        csLds[(3 * 16 + k) * 128 + col];
        const int J = (bi + t0 + k) & (NT - 1);
        atomicAdd(&density[J * NTILE + col], v);
      }
    }
  }

  // Row epilogue: reduce over 32 cols (m32), scatter; 2 atomics/row (wc=0,1).
#pragma unroll
  for (int r = 0; r < 16; r++) {
    float v = rs[r];
    v += __shfl_xor(v, 1);
    v += __shfl_xor(v, 2);
    v += __shfl_xor(v, 4);
    v += __shfl_xor(v, 8);
    v += __shfl_xor(v, 16);
    if (m32 == 0) {
      const int row = bi * NTILE + wr * 32 + (r & 3) + 8 * (r >> 2) + 4 * h;
      atomicAdd(&density[row], v);
    }
  }
#undef STAGE

  // Ticket: last finished block computes the entropy (saves 2 launches).
  __syncthreads();  // all waves' atomics issued & drained; csLds reads done
  if (tid == 0) {
    __threadfence();
    ((volatile unsigned int*)smem)[0] = atomicAdd(ticket, 1u);
  }
  __syncthreads();
  if (((volatile unsigned int*)smem)[0] == TOTAL_BLOCKS - 1) {
    __threadfence();
    float ssum = 0.0f;
    for (int i = tid; i < NROWS; i += 512) {
      const float d = __hip_atomic_load(&density[i], __ATOMIC_RELAXED,
                                        __HIP_MEMORY_SCOPE_AGENT);
      ssum += logf(d + 1e-9f);
    }
    ssum += __shfl_xor(ssum, 1);
    ssum += __shfl_xor(ssum, 2);
    ssum += __shfl_xor(ssum, 4);
    ssum += __shfl_xor(ssum, 8);
    ssum += __shfl_xor(ssum, 16);
    ssum += __shfl_xor(ssum, 32);
    float* red = ((float*)smem) + 16;
    if (lane == 0) red[wave] = ssum;
    __syncthreads();
    if (tid == 0) {
      float tot = 0.0f;
      for (int w = 0; w < 8; w++) tot += red[w];
      out[0] = -tot / (float)NROWS;
    }
  }
}

extern "C" void kernel_launch(void* const* d_in, const int* in_sizes, int n_in,
                              void* d_out, int out_size, void* d_ws, size_t ws_size,
                              hipStream_t stream) {
  const float* X = (const float*)d_in[0];
  float* out = (float*)d_out;
  char* ws = (char*)d_ws;
  unsigned int* Xn8 = (unsigned int*)ws;
  float* density = (float*)(ws + (size_t)NROWS * KDIM);
  unsigned int* ticket = (unsigned int*)(density + NROWS);

  hipFuncSetAttribute((const void*)kde_gemm,
                      hipFuncAttributeMaxDynamicSharedMemorySize, 65536);

  kde_normalize<<<NROWS / 4, 256, 0, stream>>>(X, Xn8, density, ticket);
  kde_gemm<<<dim3(NT, NSTRIP), 512, 65536, stream>>>((const unsigned char*)ws,
                                                     density, ticket, out);
}

// Round 9
// 133.290 us; speedup vs baseline: 2.6672x; 2.6672x over previous
//
#include <hip/hip_runtime.h>

// KDE entropy loss, MI355X/gfx950 — fp8 fused GEMM, symmetric pairs once,
// wrapped-diagonal mapping. 512-thread blocks (8 waves 4x2 over 128x128,
// wave tile 32x64), A-in-registers, double-buffered B, 1 barrier/iter
// (R7 structure, rolled loop — R8's full unroll + 16 live regs spilled).
// R9: in-loop colsum atomics go to an 8 KB LDS stash (ds_add, ~120cyc drain)
// instead of global density (global write-ack drained at every barrier);
// stash scattered to density once after the loop. Extra t=64 tile peeled.
// ws: [0,4MiB) Xn fp8 [16384][256]; [4MiB,+64KiB) density f32; then ticket u32.

#define NROWS 16384
#define KDIM 256            // bytes per fp8 row
#define NTILE 128
#define NT (NROWS / NTILE)  // 128 tile rows
#define NSTRIP 4
#define TOTAL_BLOCKS (NT * NSTRIP)  // 512 blocks of 512 thr = exactly 2 per CU

// sqrt(5 * log2(e)): folded into both operands -> sim scaled by 5*log2(e),
// so kernel = exp2(sim_scaled) = exp(5*sim).
#define SQRT_KLOG2E 2.68579577857f

typedef int i32x4_t __attribute__((ext_vector_type(4)));
typedef int i32x8_t __attribute__((ext_vector_type(8)));
typedef float f32x16_t __attribute__((ext_vector_type(16)));
typedef __attribute__((address_space(1))) const void global_cvoid_t;
typedef __attribute__((address_space(3))) void lds_void_t;

#if __has_builtin(__builtin_amdgcn_exp2f)
#define EXP2(x) __builtin_amdgcn_exp2f(x)
#else
#define EXP2(x) exp2f(x)
#endif

union frag8 { i32x8_t v8; i32x4_t v4[2]; };

// One wave per row: sqrt(5log2e)/max(||x||,eps), fp8 e4m3 out; zero density+ticket.
__global__ __launch_bounds__(256)
void kde_normalize(const float* __restrict__ X, unsigned int* __restrict__ Xn8,
                   float* __restrict__ density, unsigned int* __restrict__ ticket) {
  const int wave = threadIdx.x >> 6;
  const int lane = threadIdx.x & 63;
  const int row = blockIdx.x * 4 + wave;
  const float4 v = ((const float4*)(X + (size_t)row * KDIM))[lane];
  float ss = v.x * v.x + v.y * v.y + v.z * v.z + v.w * v.w;
  ss += __shfl_xor(ss, 1);
  ss += __shfl_xor(ss, 2);
  ss += __shfl_xor(ss, 4);
  ss += __shfl_xor(ss, 8);
  ss += __shfl_xor(ss, 16);
  ss += __shfl_xor(ss, 32);
  const float scale = SQRT_KLOG2E / fmaxf(sqrtf(ss), 1e-12f);
  int p = 0;
  p = __builtin_amdgcn_cvt_pk_fp8_f32(v.x * scale, v.y * scale, p, false);
  p = __builtin_amdgcn_cvt_pk_fp8_f32(v.z * scale, v.w * scale, p, true);
  Xn8[(size_t)row * 64 + lane] = (unsigned int)p;
  if (threadIdx.x < 4) density[blockIdx.x * 4 + threadIdx.x] = 0.0f;
  if (blockIdx.x == 0 && threadIdx.x == 0) *ticket = 0u;
}

// Block (bi, s): row tile bi; J = (bi+t) mod 128, t in [s*16, s*16+16)
// (+ t=64 peeled for s==0, bi<64). Each unordered tile pair once.
__global__ __launch_bounds__(512, 4)
void kde_gemm(const unsigned char* __restrict__ Xn8, float* __restrict__ density,
              unsigned int* __restrict__ ticket, float* __restrict__ out) {
  extern __shared__ char smem[];
  char* buf0 = smem;                      // 32 KB
  char* buf1 = smem + 32768;              // 32 KB
  float* csLds = (float*)(smem + 65536);  // 8 KB: [k(16)][col(128)]

  const int tid = threadIdx.x;
  const int wave = tid >> 6;   // 0..7
  const int lane = tid & 63;
  const int wr = wave >> 1;    // row quarter 0..3 (32 rows each)
  const int wc = wave & 1;     // col half 0..1 (64 cols each)
  const int m32 = lane & 31;
  const int h = lane >> 5;
  const int bi = blockIdx.x;
  const int s = blockIdx.y;
  const int t0 = s * 16;
  const bool extra = (s == 0 && bi < NT / 2);
  const char* Xb = (const char*)Xn8;

  // Chunk c = rt*8 + kb*2 + hh: lane holds M[rt*32+m32][kb*64+h*32+hh*16 ..+15].
#define STAGE(base_row, dst)                                                      \
  for (int c = wave; c < 32; c += 8) {                                            \
    const int rt = c >> 3, kb = (c >> 1) & 3, hh = c & 1;                         \
    const size_t gofs =                                                           \
        (size_t)((base_row) + rt * 32 + m32) * KDIM + kb * 64 + h * 32 + hh * 16; \
    __builtin_amdgcn_global_load_lds((global_cvoid_t*)(Xb + gofs),                \
                                     (lds_void_t*)((dst) + c * 1024), 16, 0, 0);  \
  }

  STAGE(bi * NTILE, buf0);                      // A tile -> buf0
  STAGE(((bi + t0) & (NT - 1)) * NTILE, buf1);  // B(0)   -> buf1
  // Zero the colsum stash (ds_add accumulates into it).
  for (int i = tid; i < 16 * 128; i += 512) csLds[i] = 0.0f;
  __syncthreads();  // A + B(0) landed; stash zeroed

  // A fragments -> registers: this wave's 32 rows, full K (32 VGPRs).
  frag8 areg[4];
#pragma unroll
  for (int kb = 0; kb < 4; kb++) {
    const char* pa = buf0 + (wr * 8 + kb * 2) * 1024 + lane * 16;
    areg[kb].v4[0] = *(const i32x4_t*)pa;
    areg[kb].v4[1] = *(const i32x4_t*)(pa + 1024);
  }
  __syncthreads();  // all waves done reading A from buf0

  float rs[16];
#pragma unroll
  for (int r = 0; r < 16; r++) rs[r] = 0.0f;

  for (int k = 0; k < 16; ++k) {
    char* rbuf = (k & 1) ? buf0 : buf1;  // B(k): landed at last barrier
    char* sbuf = (k & 1) ? buf1 : buf0;  // free since last barrier

    if (k < 15) {
      STAGE(((bi + t0 + k + 1) & (NT - 1)) * NTILE, sbuf);
    } else if (extra) {
      STAGE(((bi + 64) & (NT - 1)) * NTILE, sbuf);  // sbuf == buf1 at k==15
    }

    f32x16_t acc[2];
#pragma unroll
    for (int j = 0; j < 2; j++) acc[j] = (f32x16_t)0.0f;

#pragma unroll
    for (int kb = 0; kb < 4; ++kb) {
      frag8 bf[2];
#pragma unroll
      for (int j = 0; j < 2; j++) {
        const char* pb = rbuf + ((wc * 2 + j) * 8 + kb * 2) * 1024 + lane * 16;
        bf[j].v4[0] = *(const i32x4_t*)pb;
        bf[j].v4[1] = *(const i32x4_t*)(pb + 1024);
      }
#pragma unroll
      for (int j = 0; j < 2; j++)
        acc[j] = __builtin_amdgcn_mfma_scale_f32_32x32x64_f8f6f4(
            areg[kb].v8, bf[j].v8, acc[j], 0, 0, 0, 127, 0, 127);
    }

    // Epilogue: e = exp2(sim_scaled) = exp(5*sim). rowsums in regs across k;
    // colsums -> LDS stash (no vmem in loop: barrier drains only staging +
    // cheap lgkm). C/D: col = m32 (j-block), row = (r&3) + 8*(r>>2) + 4*h.
    float c0 = 0.0f, c1 = 0.0f;
#pragma unroll
    for (int r = 0; r < 16; r++) {
      const float e0 = EXP2(acc[0][r]);
      const float e1 = EXP2(acc[1][r]);
      rs[r] += e0 + e1;
      c0 += e0;
      c1 += e1;
    }
    c0 += __shfl_xor(c0, 32);  // combine h halves -> 32-row column partial
    c1 += __shfl_xor(c1, 32);
    if ((s != 0 || k != 0) && h == 0) {  // t==0 diagonal: rowsum only
      atomicAdd(&csLds[k * 128 + wc * 64 + m32], c0);
      atomicAdd(&csLds[k * 128 + wc * 64 + 32 + m32], c1);
    }

    __syncthreads();  // B(k+1) landed; all waves done reading rbuf
  }

  // Peeled extra tile t=64 (bi<64, s==0): immediate colsum atomics (once).
  if (extra) {
    const int J = (bi + 64) & (NT - 1);
    f32x16_t acc[2];
#pragma unroll
    for (int j = 0; j < 2; j++) acc[j] = (f32x16_t)0.0f;
#pragma unroll
    for (int kb = 0; kb < 4; ++kb) {
      frag8 bf[2];
#pragma unroll
      for (int j = 0; j < 2; j++) {
        const char* pb = buf1 + ((wc * 2 + j) * 8 + kb * 2) * 1024 + lane * 16;
        bf[j].v4[0] = *(const i32x4_t*)pb;
        bf[j].v4[1] = *(const i32x4_t*)(pb + 1024);
      }
#pragma unroll
      for (int j = 0; j < 2; j++)
        acc[j] = __builtin_amdgcn_mfma_scale_f32_32x32x64_f8f6f4(
            areg[kb].v8, bf[j].v8, acc[j], 0, 0, 0, 127, 0, 127);
    }
    float c0 = 0.0f, c1 = 0.0f;
#pragma unroll
    for (int r = 0; r < 16; r++) {
      const float e0 = EXP2(acc[0][r]);
      const float e1 = EXP2(acc[1][r]);
      rs[r] += e0 + e1;
      c0 += e0;
      c1 += e1;
    }
    c0 += __shfl_xor(c0, 32);
    c1 += __shfl_xor(c1, 32);
    if (h == 0) {
      atomicAdd(&density[J * NTILE + wc * 64 + m32], c0);
      atomicAdd(&density[J * NTILE + wc * 64 + 32 + m32], c1);
    }
  }

  // Deferred colsum scatter: stash -> density (2048 global atomics/block).
  // Loop-end barrier already ordered all ds_adds.
  for (int i = 0; i < 4; ++i) {
    const int idx = tid + i * 512;   // 0..2047
    const int k = idx >> 7, col = idx & 127;
    if (s != 0 || k != 0) {          // diagonal slot never written
      const int J = (bi + t0 + k) & (NT - 1);
      atomicAdd(&density[J * NTILE + col], csLds[idx]);
    }
  }

  // Row epilogue: reduce over 32 cols (m32), scatter; 2 atomics/row (wc=0,1).
#pragma unroll
  for (int r = 0; r < 16; r++) {
    float v = rs[r];
    v += __shfl_xor(v, 1);
    v += __shfl_xor(v, 2);
    v += __shfl_xor(v, 4);
    v += __shfl_xor(v, 8);
    v += __shfl_xor(v, 16);
    if (m32 == 0) {
      const int row = bi * NTILE + wr * 32 + (r & 3) + 8 * (r >> 2) + 4 * h;
      atomicAdd(&density[row], v);
    }
  }
#undef STAGE

  // Ticket: last finished block computes the entropy (saves 2 launches).
  __syncthreads();  // all waves' atomics issued & drained
  if (tid == 0) {
    __threadfence();
    ((volatile unsigned int*)smem)[0] = atomicAdd(ticket, 1u);
  }
  __syncthreads();
  if (((volatile unsigned int*)smem)[0] == TOTAL_BLOCKS - 1) {
    __threadfence();
    float ssum = 0.0f;
    for (int i = tid; i < NROWS; i += 512) {
      const float d = __hip_atomic_load(&density[i], __ATOMIC_RELAXED,
                                        __HIP_MEMORY_SCOPE_AGENT);
      ssum += logf(d + 1e-9f);
    }
    ssum += __shfl_xor(ssum, 1);
    ssum += __shfl_xor(ssum, 2);
    ssum += __shfl_xor(ssum, 4);
    ssum += __shfl_xor(ssum, 8);
    ssum += __shfl_xor(ssum, 16);
    ssum += __shfl_xor(ssum, 32);
    float* red = ((float*)smem) + 16;
    if (lane == 0) red[wave] = ssum;
    __syncthreads();
    if (tid == 0) {
      float tot = 0.0f;
      for (int w = 0; w < 8; w++) tot += red[w];
      out[0] = -tot / (float)NROWS;
    }
  }
}

extern "C" void kernel_launch(void* const* d_in, const int* in_sizes, int n_in,
                              void* d_out, int out_size, void* d_ws, size_t ws_size,
                              hipStream_t stream) {
  const float* X = (const float*)d_in[0];
  float* out = (float*)d_out;
  char* ws = (char*)d_ws;
  unsigned int* Xn8 = (unsigned int*)ws;
  float* density = (float*)(ws + (size_t)NROWS * KDIM);
  unsigned int* ticket = (unsigned int*)(density + NROWS);

  hipFuncSetAttribute((const void*)kde_gemm,
                      hipFuncAttributeMaxDynamicSharedMemorySize, 73728);

  kde_normalize<<<NROWS / 4, 256, 0, stream>>>(X, Xn8, density, ticket);
  kde_gemm<<<dim3(NT, NSTRIP), 512, 73728, stream>>>((const unsigned char*)ws,
                                                     density, ticket, out);
}